// Round 1
// baseline (1146.160 us; speedup 1.0000x reference)
//
#include <hip/hip_runtime.h>
#include <math.h>

namespace {

constexpr int B_ = 32, K_ = 512, L_ = 6, D_ = 2048, H_ = 16, HD_ = 128;
constexpr int OBS_ = 128, MAXS_ = 512, A_ = 10;
constexpr int NCH = 32, KC = K_ / NCH;           // 32 chunks of 16 keys
constexpr float EPS = 1e-5f;
constexpr float INV_SCALE = 0.022097086912079608f; // 1/sqrt(2048)

__device__ __forceinline__ float wsum64(float v) {
  v += __shfl_xor(v, 32); v += __shfl_xor(v, 16); v += __shfl_xor(v, 8);
  v += __shfl_xor(v, 4);  v += __shfl_xor(v, 2);  v += __shfl_xor(v, 1);
  return v;
}

// ---------------- positional encoding table [MAXS, D] ----------------
__global__ __launch_bounds__(256) void k_pe(float* __restrict__ pe) {
  int s = blockIdx.x, t = threadIdx.x;
  float seqv = (float)(MAXS_ - 1 - s);
  const float c = 13.287712379549449f / 1024.0f; // log2(10000)/1024
  for (int r = 0; r < 8; ++r) {
    int j = t + 256 * r;
    int i = (j < 1024) ? j : j - 1024;
    float inv = exp2f(-c * (float)i);
    float a = seqv * inv;
    pe[(size_t)s * D_ + j] = (j < 1024) ? sinf(a) : cosf(a);
  }
}

// ---------------- encoder: h = x @ enc_w^T + enc_b ----------------
__global__ __launch_bounds__(128) void k_enc(const float* __restrict__ x,
                                             const float* __restrict__ ew,
                                             const float* __restrict__ eb,
                                             float* __restrict__ h) {
  int b = blockIdx.x, et = blockIdx.y, t = threadIdx.x;
  __shared__ float xs[OBS_];
  xs[t] = x[b * OBS_ + t];
  __syncthreads();
  int e = et * 128 + t;
  const float* wr = ew + (size_t)e * OBS_;
  float acc = eb[e];
  for (int o = 0; o < OBS_; ++o) acc += xs[o] * wr[o];
  h[(size_t)b * D_ + e] = acc;
}

// ---------------- per layer: q_ = LN(h), q = Wq q_, qW = inv_scale * Wk^T q ----------------
__global__ __launch_bounds__(256) void k_qw(const float* __restrict__ h,
                                            const float* __restrict__ g,
                                            const float* __restrict__ bvec,
                                            const float* __restrict__ Wq,
                                            const float* __restrict__ Wk,
                                            float* __restrict__ qW) {
  int b = blockIdx.x, t = threadIdx.x;
  int lane = t & 63, wv = t >> 6;
  __shared__ float qn[D_];
  __shared__ float qs[D_];
  __shared__ float rs[4], rq[4];
  // load 8 elems of h row, stats
  float4 v0 = *(const float4*)(h + (size_t)b * D_ + t * 8);
  float4 v1 = *(const float4*)(h + (size_t)b * D_ + t * 8 + 4);
  float ls = v0.x + v0.y + v0.z + v0.w + v1.x + v1.y + v1.z + v1.w;
  float lq = v0.x * v0.x + v0.y * v0.y + v0.z * v0.z + v0.w * v0.w +
             v1.x * v1.x + v1.y * v1.y + v1.z * v1.z + v1.w * v1.w;
  ls = wsum64(ls); lq = wsum64(lq);
  if (lane == 0) { rs[wv] = ls; rq[wv] = lq; }
  __syncthreads();
  float sum = rs[0] + rs[1] + rs[2] + rs[3];
  float sq  = rq[0] + rq[1] + rq[2] + rq[3];
  float mean = sum * (1.f / D_);
  float rstd = rsqrtf(sq * (1.f / D_) - mean * mean + EPS);
  {
    float4 g0 = *(const float4*)(g + t * 8);
    float4 g1 = *(const float4*)(g + t * 8 + 4);
    float4 b0 = *(const float4*)(bvec + t * 8);
    float4 b1 = *(const float4*)(bvec + t * 8 + 4);
    qn[t * 8 + 0] = (v0.x - mean) * rstd * g0.x + b0.x;
    qn[t * 8 + 1] = (v0.y - mean) * rstd * g0.y + b0.y;
    qn[t * 8 + 2] = (v0.z - mean) * rstd * g0.z + b0.z;
    qn[t * 8 + 3] = (v0.w - mean) * rstd * g0.w + b0.w;
    qn[t * 8 + 4] = (v1.x - mean) * rstd * g1.x + b1.x;
    qn[t * 8 + 5] = (v1.y - mean) * rstd * g1.y + b1.y;
    qn[t * 8 + 6] = (v1.z - mean) * rstd * g1.z + b1.z;
    qn[t * 8 + 7] = (v1.w - mean) * rstd * g1.w + b1.w;
  }
  __syncthreads();
  // stage 1: q[h*HD+e] = sum_d qn[h*HD+d] * Wq[e*HD+d]; quarter-wave per head
  int qid = t >> 4;        // 0..15 == head
  int li = t & 15;
  for (int it = 0; it < 128; ++it) {
    int e = it;
    const float4* wr = (const float4*)(Wq + (size_t)e * HD_ + li * 8);
    const float4* qv = (const float4*)(qn + qid * HD_ + li * 8);
    float4 w0 = wr[0], w1 = wr[1], a0 = qv[0], a1 = qv[1];
    float acc = w0.x * a0.x + w0.y * a0.y + w0.z * a0.z + w0.w * a0.w +
                w1.x * a1.x + w1.y * a1.y + w1.z * a1.z + w1.w * a1.w;
    acc += __shfl_xor(acc, 1); acc += __shfl_xor(acc, 2);
    acc += __shfl_xor(acc, 4); acc += __shfl_xor(acc, 8);
    if (li == 0) qs[qid * HD_ + e] = acc;
  }
  __syncthreads();
  // stage 2: qW[h*HD+d] = inv_scale * sum_e qs[h*HD+e] * Wk[e*HD+d]  (coalesced over d)
  for (int r = 0; r < 8; ++r) {
    int j = t + 256 * r;
    int hh = j >> 7, d = j & 127;
    const float* qv = qs + hh * HD_;
    float acc = 0.f;
    for (int e = 0; e < HD_; ++e) acc += qv[e] * Wk[(size_t)e * HD_ + d];
    qW[(size_t)b * D_ + j] = acc * INV_SCALE;
  }
}

// ---------------- attention: one pass over memories, online softmax, split-K partials --------
__global__ __launch_bounds__(512) void k_attn(const float* __restrict__ mem,
                                              const float* __restrict__ pe,
                                              const int* __restrict__ mask,
                                              const int* __restrict__ midx,
                                              const float* __restrict__ g,
                                              const float* __restrict__ bvec,
                                              const float* __restrict__ qW,
                                              float* __restrict__ pm,
                                              float* __restrict__ ps,
                                              float* __restrict__ pctx,
                                              int layer) {
  int b = blockIdx.x, ch = blockIdx.y;
  int t = threadIdx.x;
  int lane = t & 63, wv = t >> 6;
  int hh = t >> 5;       // head (0..15); half-wave owns one head
  int li = t & 31;       // lane within head; covers d_local = 4*li .. 4*li+3
  __shared__ float redS[2][8], redQ[2][8];

  float4 g4 = *(const float4*)(g + t * 4);
  float4 b4 = *(const float4*)(bvec + t * 4);
  float4 qw4 = *(const float4*)(qW + (size_t)b * D_ + t * 4);

  float mrun = -INFINITY, srun = 0.f;
  float4 ctx = {0.f, 0.f, 0.f, 0.f};
  int it = 0;
  const size_t browbase = ((size_t)b * K_) * (L_ * D_) + (size_t)layer * D_;

  for (int kk = ch * KC; kk < ch * KC + KC; ++kk) {
    if (mask[b * K_ + kk] == 0) continue;    // block-uniform
    int pidx = midx[b * K_ + kk];
    float4 xm = *(const float4*)(mem + browbase + (size_t)kk * (L_ * D_) + t * 4);
    float4 xp = *(const float4*)(pe + (size_t)pidx * D_ + t * 4);
    float4 x = {xm.x + xp.x, xm.y + xp.y, xm.z + xp.z, xm.w + xp.w};
    float lsv = x.x + x.y + x.z + x.w;
    float lqv = x.x * x.x + x.y * x.y + x.z * x.z + x.w * x.w;
    lsv = wsum64(lsv); lqv = wsum64(lqv);
    int p = it & 1;
    if (lane == 0) { redS[p][wv] = lsv; redQ[p][wv] = lqv; }
    __syncthreads();
    float sum = 0.f, sq = 0.f;
    #pragma unroll
    for (int w = 0; w < 8; ++w) { sum += redS[p][w]; sq += redQ[p][w]; }
    float mean = sum * (1.f / D_);
    float rstd = rsqrtf(sq * (1.f / D_) - mean * mean + EPS);
    float4 kv;
    kv.x = (x.x - mean) * rstd * g4.x + b4.x;
    kv.y = (x.y - mean) * rstd * g4.y + b4.y;
    kv.z = (x.z - mean) * rstd * g4.z + b4.z;
    kv.w = (x.w - mean) * rstd * g4.w + b4.w;
    float e = kv.x * qw4.x + kv.y * qw4.y + kv.z * qw4.z + kv.w * qw4.w;
    e += __shfl_xor(e, 1); e += __shfl_xor(e, 2); e += __shfl_xor(e, 4);
    e += __shfl_xor(e, 8); e += __shfl_xor(e, 16);   // reduce within 32-lane half
    float mnew = fmaxf(mrun, e);
    float sc = __expf(mrun - mnew);
    float w = __expf(e - mnew);
    srun = srun * sc + w;
    ctx.x = ctx.x * sc + w * kv.x;
    ctx.y = ctx.y * sc + w * kv.y;
    ctx.z = ctx.z * sc + w * kv.z;
    ctx.w = ctx.w * sc + w * kv.w;
    mrun = mnew;
    ++it;
  }
  size_t base = (size_t)(b * H_ + hh) * NCH + ch;
  *(float4*)(pctx + base * HD_ + 4 * li) = ctx;
  if (li == 0) { pm[base] = mrun; ps[base] = srun; }
}

// ---------------- merge partials + apply Wv: o_pre[b, h*HD+e] ----------------
__global__ __launch_bounds__(128) void k_reduce(const float* __restrict__ pm,
                                                const float* __restrict__ ps,
                                                const float* __restrict__ pctx,
                                                const float* __restrict__ Wv,
                                                float* __restrict__ opre) {
  int hh = blockIdx.x, b = blockIdx.y;
  int t = threadIdx.x;   // 0..127 = d
  size_t base = (size_t)(b * H_ + hh) * NCH;
  float m = -INFINITY;
  for (int c = 0; c < NCH; ++c) m = fmaxf(m, pm[base + c]);
  float stot = 0.f, acc = 0.f;
  for (int c = 0; c < NCH; ++c) {
    float wc = __expf(pm[base + c] - m);
    stot += ps[base + c] * wc;
    acc += pctx[(base + c) * HD_ + t] * wc;
  }
  float ctxn = (stot > 0.f) ? acc / stot : 0.f;
  __shared__ float cs[HD_];
  cs[t] = ctxn;
  __syncthreads();
  const float* wr = Wv + (size_t)t * HD_;   // output e = t
  float o = 0.f;
  for (int d = 0; d < HD_; ++d) o += wr[d] * cs[d];
  opre[(size_t)b * D_ + hh * HD_ + t] = o;
}

// ---------------- xr = o_pre @ Wo^T + bo + h ----------------
__global__ __launch_bounds__(256) void k_wo(const float* __restrict__ opre,
                                            const float* __restrict__ Wo,
                                            const float* __restrict__ bo,
                                            const float* __restrict__ h,
                                            float* __restrict__ xr) {
  int b = blockIdx.x, et = blockIdx.y;
  int t = threadIdx.x, lane = t & 63, wv = t >> 6;
  __shared__ float xs[D_];
  for (int i = t; i < D_ / 4; i += 256)
    ((float4*)xs)[i] = ((const float4*)(opre + (size_t)b * D_))[i];
  __syncthreads();
  for (int j = 0; j < 16; ++j) {
    int e = et * 64 + wv * 16 + j;
    const float4* wr = (const float4*)(Wo + (size_t)e * D_);
    float acc = 0.f;
    for (int i = lane; i < D_ / 4; i += 64) {
      float4 w = wr[i]; float4 xv = ((float4*)xs)[i];
      acc += w.x * xv.x + w.y * xv.y + w.z * xv.z + w.w * xv.w;
    }
    acc = wsum64(acc);
    if (lane == 0) xr[(size_t)b * D_ + e] = acc + bo[e] + h[(size_t)b * D_ + e];
  }
}

// ---------------- h = relu(LN(xr) @ Fw^T + Fb) + xr ----------------
__global__ __launch_bounds__(256) void k_fc(const float* __restrict__ xr,
                                            const float* __restrict__ g,
                                            const float* __restrict__ bvec,
                                            const float* __restrict__ Fw,
                                            const float* __restrict__ Fb,
                                            float* __restrict__ hout) {
  int b = blockIdx.x, et = blockIdx.y;
  int t = threadIdx.x, lane = t & 63, wv = t >> 6;
  __shared__ float raw[D_];
  __shared__ float nrm[D_];
  __shared__ float rs[4], rq[4];
  float ls = 0.f, lq = 0.f;
  for (int i = t; i < D_ / 4; i += 256) {
    float4 v = ((const float4*)(xr + (size_t)b * D_))[i];
    ((float4*)raw)[i] = v;
    ls += v.x + v.y + v.z + v.w;
    lq += v.x * v.x + v.y * v.y + v.z * v.z + v.w * v.w;
  }
  ls = wsum64(ls); lq = wsum64(lq);
  if (lane == 0) { rs[wv] = ls; rq[wv] = lq; }
  __syncthreads();
  float sum = rs[0] + rs[1] + rs[2] + rs[3];
  float sq  = rq[0] + rq[1] + rq[2] + rq[3];
  float mean = sum * (1.f / D_);
  float rstd = rsqrtf(sq * (1.f / D_) - mean * mean + EPS);
  for (int i = t; i < D_ / 4; i += 256) {
    float4 v = ((float4*)raw)[i];
    float4 g4 = ((const float4*)g)[i];
    float4 b4 = ((const float4*)bvec)[i];
    float4 n;
    n.x = (v.x - mean) * rstd * g4.x + b4.x;
    n.y = (v.y - mean) * rstd * g4.y + b4.y;
    n.z = (v.z - mean) * rstd * g4.z + b4.z;
    n.w = (v.w - mean) * rstd * g4.w + b4.w;
    ((float4*)nrm)[i] = n;
  }
  __syncthreads();
  for (int j = 0; j < 16; ++j) {
    int e = et * 64 + wv * 16 + j;
    const float4* wr = (const float4*)(Fw + (size_t)e * D_);
    float acc = 0.f;
    for (int i = lane; i < D_ / 4; i += 64) {
      float4 w = wr[i]; float4 xv = ((float4*)nrm)[i];
      acc += w.x * xv.x + w.y * xv.y + w.z * xv.z + w.w * xv.w;
    }
    acc = wsum64(acc);
    if (lane == 0)
      hout[(size_t)b * D_ + e] = fmaxf(acc + Fb[e], 0.f) + raw[e];
  }
}

// ---------------- hid = relu(h @ post_w^T + post_b) ----------------
__global__ __launch_bounds__(256) void k_post(const float* __restrict__ h,
                                              const float* __restrict__ Pw,
                                              const float* __restrict__ Pb,
                                              float* __restrict__ hid) {
  int b = blockIdx.x, et = blockIdx.y;
  int t = threadIdx.x, lane = t & 63, wv = t >> 6;
  __shared__ float xs[D_];
  for (int i = t; i < D_ / 4; i += 256)
    ((float4*)xs)[i] = ((const float4*)(h + (size_t)b * D_))[i];
  __syncthreads();
  for (int j = 0; j < 16; ++j) {
    int e = et * 64 + wv * 16 + j;
    const float4* wr = (const float4*)(Pw + (size_t)e * D_);
    float acc = 0.f;
    for (int i = lane; i < D_ / 4; i += 64) {
      float4 w = wr[i]; float4 xv = ((float4*)xs)[i];
      acc += w.x * xv.x + w.y * xv.y + w.z * xv.z + w.w * xv.w;
    }
    acc = wsum64(acc);
    if (lane == 0) hid[(size_t)b * D_ + e] = fmaxf(acc + Pb[e], 0.f);
  }
}

// ---------------- heads: out[b, 0..9]=actor, out[b,10]=critic ----------------
__global__ __launch_bounds__(256) void k_heads(const float* __restrict__ hid,
                                               const float* __restrict__ aw,
                                               const float* __restrict__ ab,
                                               const float* __restrict__ cw,
                                               const float* __restrict__ cb,
                                               float* __restrict__ out) {
  int b = blockIdx.x, j = blockIdx.y;
  int t = threadIdx.x, lane = t & 63, wv = t >> 6;
  const float* wr = (j < A_) ? (aw + (size_t)j * D_) : cw;
  float acc = 0.f;
  for (int i = t; i < D_ / 4; i += 256) {
    float4 w = ((const float4*)wr)[i];
    float4 xv = ((const float4*)(hid + (size_t)b * D_))[i];
    acc += w.x * xv.x + w.y * xv.y + w.z * xv.z + w.w * xv.w;
  }
  acc = wsum64(acc);
  __shared__ float r[4];
  if (lane == 0) r[wv] = acc;
  __syncthreads();
  if (t == 0) {
    float s = r[0] + r[1] + r[2] + r[3] + ((j < A_) ? ab[j] : cb[0]);
    out[b * (A_ + 1) + j] = s;
  }
}

} // namespace

extern "C" void kernel_launch(void* const* d_in, const int* in_sizes, int n_in,
                              void* d_out, int out_size, void* d_ws, size_t ws_size,
                              hipStream_t stream) {
  (void)in_sizes; (void)n_in; (void)out_size; (void)ws_size;
  const float* x      = (const float*)d_in[0];
  const float* mem    = (const float*)d_in[1];
  const int*   mask   = (const int*)d_in[2];
  const int*   midx   = (const int*)d_in[3];
  const float* enc_w  = (const float*)d_in[4];
  const float* enc_b  = (const float*)d_in[5];
  const float* lnq_g  = (const float*)d_in[6];
  const float* lnq_b  = (const float*)d_in[7];
  const float* lnkv_g = (const float*)d_in[8];
  const float* lnkv_b = (const float*)d_in[9];
  const float* lnat_g = (const float*)d_in[10];
  const float* lnat_b = (const float*)d_in[11];
  const float* wq     = (const float*)d_in[12];
  const float* wk     = (const float*)d_in[13];
  const float* wv     = (const float*)d_in[14];
  const float* wo     = (const float*)d_in[15];
  const float* bo     = (const float*)d_in[16];
  const float* fc_w   = (const float*)d_in[17];
  const float* fc_b   = (const float*)d_in[18];
  const float* post_w = (const float*)d_in[19];
  const float* post_b = (const float*)d_in[20];
  const float* act_w  = (const float*)d_in[21];
  const float* act_b  = (const float*)d_in[22];
  const float* cri_w  = (const float*)d_in[23];
  const float* cri_b  = (const float*)d_in[24];
  float* out = (float*)d_out;

  float* ws = (float*)d_ws;
  size_t off = 0;
  float* pe   = ws + off; off += (size_t)MAXS_ * D_;        // 1,048,576
  float* h    = ws + off; off += (size_t)B_ * D_;           // 65,536
  float* qW   = ws + off; off += (size_t)B_ * D_;
  float* opre = ws + off; off += (size_t)B_ * D_;
  float* xr   = ws + off; off += (size_t)B_ * D_;
  float* pm   = ws + off; off += (size_t)B_ * H_ * NCH;
  float* ps   = ws + off; off += (size_t)B_ * H_ * NCH;
  float* pctx = ws + off; off += (size_t)B_ * H_ * NCH * HD_; // 2,097,152
  float* hid  = ws + off; off += (size_t)B_ * D_;

  hipLaunchKernelGGL(k_pe, dim3(MAXS_), dim3(256), 0, stream, pe);
  hipLaunchKernelGGL(k_enc, dim3(B_, D_ / 128), dim3(128), 0, stream, x, enc_w, enc_b, h);

  for (int l = 0; l < L_; ++l) {
    const float* Wq = wq + (size_t)l * HD_ * HD_;
    const float* Wk = wk + (size_t)l * HD_ * HD_;
    const float* Wv = wv + (size_t)l * HD_ * HD_;
    const float* Wo = wo + (size_t)l * D_ * D_;
    const float* Fw = fc_w + (size_t)l * D_ * D_;
    hipLaunchKernelGGL(k_qw, dim3(B_), dim3(256), 0, stream,
                       h, lnq_g + (size_t)l * D_, lnq_b + (size_t)l * D_, Wq, Wk, qW);
    hipLaunchKernelGGL(k_attn, dim3(B_, NCH), dim3(512), 0, stream,
                       mem, pe, mask, midx,
                       lnkv_g + (size_t)l * D_, lnkv_b + (size_t)l * D_,
                       qW, pm, ps, pctx, l);
    hipLaunchKernelGGL(k_reduce, dim3(H_, B_), dim3(128), 0, stream,
                       pm, ps, pctx, Wv, opre);
    hipLaunchKernelGGL(k_wo, dim3(B_, D_ / 64), dim3(256), 0, stream,
                       opre, Wo, bo + (size_t)l * D_, h, xr);
    hipLaunchKernelGGL(k_fc, dim3(B_, D_ / 64), dim3(256), 0, stream,
                       xr, lnat_g + (size_t)l * D_, lnat_b + (size_t)l * D_,
                       Fw, fc_b + (size_t)l * D_, h);
  }

  hipLaunchKernelGGL(k_post, dim3(B_, D_ / 64), dim3(256), 0, stream, h, post_w, post_b, hid);
  hipLaunchKernelGGL(k_heads, dim3(B_, A_ + 1), dim3(256), 0, stream,
                     hid, act_w, act_b, cri_w, cri_b, out);
}

// Round 2
// 1076.761 us; speedup vs baseline: 1.0645x; 1.0645x over previous
//
#include <hip/hip_runtime.h>
#include <math.h>

namespace {

constexpr int B_ = 32, K_ = 512, L_ = 6, D_ = 2048, H_ = 16, HD_ = 128;
constexpr int OBS_ = 128, MAXS_ = 512, A_ = 10;
constexpr int NCH = 64, WKEYS = 8;               // 64 chunks of 8 keys, one wave each
constexpr int KSPLIT = 8, KCHUNK = 256;          // matmul k-split
constexpr float EPS = 1e-5f;
constexpr float INV_SCALE = 0.022097086912079608f; // 1/sqrt(2048)

__device__ __forceinline__ float wsum64(float v) {
  v += __shfl_xor(v, 32); v += __shfl_xor(v, 16); v += __shfl_xor(v, 8);
  v += __shfl_xor(v, 4);  v += __shfl_xor(v, 2);  v += __shfl_xor(v, 1);
  return v;
}

// ---------------- positional encoding table [MAXS, D] ----------------
__global__ __launch_bounds__(256) void k_pe(float* __restrict__ pe) {
  int s = blockIdx.x, t = threadIdx.x;
  float seqv = (float)(MAXS_ - 1 - s);
  const float c = 13.287712379549449f / 1024.0f; // log2(10000)/1024
  for (int r = 0; r < 8; ++r) {
    int j = t + 256 * r;
    int i = (j < 1024) ? j : j - 1024;
    float inv = exp2f(-c * (float)i);
    float a = seqv * inv;
    pe[(size_t)s * D_ + j] = (j < 1024) ? sinf(a) : cosf(a);
  }
}

// ---------------- encoder: h = x @ enc_w^T + enc_b ----------------
__global__ __launch_bounds__(128) void k_enc(const float* __restrict__ x,
                                             const float* __restrict__ ew,
                                             const float* __restrict__ eb,
                                             float* __restrict__ h) {
  int b = blockIdx.x, et = blockIdx.y, t = threadIdx.x;
  __shared__ float xs[OBS_];
  xs[t] = x[b * OBS_ + t];
  __syncthreads();
  int e = et * 128 + t;
  const float* wr = ew + (size_t)e * OBS_;
  float acc = eb[e];
  for (int o = 0; o < OBS_; ++o) acc += xs[o] * wr[o];
  h[(size_t)b * D_ + e] = acc;
}

// ---------------- per layer: q_=LN(h), q=Wq q_, qW = inv_scale * Wk^T q ----------------
__global__ __launch_bounds__(256) void k_qw(const float* __restrict__ h,
                                            const float* __restrict__ g,
                                            const float* __restrict__ bvec,
                                            const float* __restrict__ Wq,
                                            const float* __restrict__ Wk,
                                            float* __restrict__ qW) {
  int b = blockIdx.x, t = threadIdx.x;
  int lane = t & 63, wv = t >> 6;
  __shared__ float qn[D_];
  __shared__ float qs[D_];
  __shared__ float rs[4], rq[4];
  float4 v0 = *(const float4*)(h + (size_t)b * D_ + t * 8);
  float4 v1 = *(const float4*)(h + (size_t)b * D_ + t * 8 + 4);
  float ls = v0.x + v0.y + v0.z + v0.w + v1.x + v1.y + v1.z + v1.w;
  float lq = v0.x * v0.x + v0.y * v0.y + v0.z * v0.z + v0.w * v0.w +
             v1.x * v1.x + v1.y * v1.y + v1.z * v1.z + v1.w * v1.w;
  ls = wsum64(ls); lq = wsum64(lq);
  if (lane == 0) { rs[wv] = ls; rq[wv] = lq; }
  __syncthreads();
  float sum = rs[0] + rs[1] + rs[2] + rs[3];
  float sq  = rq[0] + rq[1] + rq[2] + rq[3];
  float mean = sum * (1.f / D_);
  float rstd = rsqrtf(sq * (1.f / D_) - mean * mean + EPS);
  {
    float4 g0 = *(const float4*)(g + t * 8);
    float4 g1 = *(const float4*)(g + t * 8 + 4);
    float4 b0 = *(const float4*)(bvec + t * 8);
    float4 b1 = *(const float4*)(bvec + t * 8 + 4);
    qn[t * 8 + 0] = (v0.x - mean) * rstd * g0.x + b0.x;
    qn[t * 8 + 1] = (v0.y - mean) * rstd * g0.y + b0.y;
    qn[t * 8 + 2] = (v0.z - mean) * rstd * g0.z + b0.z;
    qn[t * 8 + 3] = (v0.w - mean) * rstd * g0.w + b0.w;
    qn[t * 8 + 4] = (v1.x - mean) * rstd * g1.x + b1.x;
    qn[t * 8 + 5] = (v1.y - mean) * rstd * g1.y + b1.y;
    qn[t * 8 + 6] = (v1.z - mean) * rstd * g1.z + b1.z;
    qn[t * 8 + 7] = (v1.w - mean) * rstd * g1.w + b1.w;
  }
  __syncthreads();
  int qid = t >> 4;
  int li = t & 15;
  for (int e = 0; e < 128; ++e) {
    const float4* wr = (const float4*)(Wq + (size_t)e * HD_ + li * 8);
    const float4* qv = (const float4*)(qn + qid * HD_ + li * 8);
    float4 w0 = wr[0], w1 = wr[1], a0 = qv[0], a1 = qv[1];
    float acc = w0.x * a0.x + w0.y * a0.y + w0.z * a0.z + w0.w * a0.w +
                w1.x * a1.x + w1.y * a1.y + w1.z * a1.z + w1.w * a1.w;
    acc += __shfl_xor(acc, 1); acc += __shfl_xor(acc, 2);
    acc += __shfl_xor(acc, 4); acc += __shfl_xor(acc, 8);
    if (li == 0) qs[qid * HD_ + e] = acc;
  }
  __syncthreads();
  for (int r = 0; r < 8; ++r) {
    int j = t + 256 * r;
    int hh = j >> 7, d = j & 127;
    const float* qv = qs + hh * HD_;
    float acc = 0.f;
    for (int e = 0; e < HD_; ++e) acc += qv[e] * Wk[(size_t)e * HD_ + d];
    qW[(size_t)b * D_ + j] = acc * INV_SCALE;
  }
}

// ---------------- attention: wave-autonomous, 8 keys/wave, no barriers in loop --------
__global__ __launch_bounds__(256) void k_attn(const float* __restrict__ mem,
                                              const float* __restrict__ pe,
                                              const int* __restrict__ mask,
                                              const int* __restrict__ midx,
                                              const float* __restrict__ g,
                                              const float* __restrict__ bvec,
                                              const float* __restrict__ qW,
                                              float* __restrict__ pm,
                                              float* __restrict__ ps,
                                              float* __restrict__ pctx,
                                              int layer) {
  int b = blockIdx.x;
  int t = threadIdx.x;
  int wid = t >> 6, l = t & 63;
  int ch = blockIdx.y * 4 + wid;     // 0..63
  int hi = l >> 5;                   // which head within chunk pair
  int ll = l & 31;

  __shared__ float gs[D_], bs[D_], qs[D_];
  for (int i = t; i < D_ / 4; i += 256) {
    ((float4*)gs)[i] = ((const float4*)g)[i];
    ((float4*)bs)[i] = ((const float4*)bvec)[i];
    ((float4*)qs)[i] = ((const float4*)(qW + (size_t)b * D_))[i];
  }
  __syncthreads();

  float m[8], s[8];
  float4 ctx[8];
  #pragma unroll
  for (int i = 0; i < 8; ++i) {
    m[i] = -INFINITY; s[i] = 0.f; ctx[i] = {0.f, 0.f, 0.f, 0.f};
  }

  const size_t browbase = ((size_t)b * K_) * (L_ * D_) + (size_t)layer * D_;
  int kk0 = ch * WKEYS;
  for (int kk = kk0; kk < kk0 + WKEYS; ++kk) {
    if (mask[b * K_ + kk] == 0) continue;  // wave-uniform
    int pidx = midx[b * K_ + kk];
    const float4* mp = (const float4*)(mem + browbase + (size_t)kk * (L_ * D_));
    const float4* pp = (const float4*)(pe + (size_t)pidx * D_);
    float4 x[8];
    #pragma unroll
    for (int i = 0; i < 8; ++i) {
      float4 a = mp[i * 64 + l];
      float4 c = pp[i * 64 + l];
      x[i] = {a.x + c.x, a.y + c.y, a.z + c.z, a.w + c.w};
    }
    float ls = 0.f, lq = 0.f;
    #pragma unroll
    for (int i = 0; i < 8; ++i) {
      ls += x[i].x + x[i].y + x[i].z + x[i].w;
      lq += x[i].x * x[i].x + x[i].y * x[i].y + x[i].z * x[i].z + x[i].w * x[i].w;
    }
    ls = wsum64(ls); lq = wsum64(lq);
    float mean = ls * (1.f / D_);
    float rstd = rsqrtf(lq * (1.f / D_) - mean * mean + EPS);
    #pragma unroll
    for (int i = 0; i < 8; ++i) {
      int idx = i * 64 + l;
      float4 g4 = ((const float4*)gs)[idx];
      float4 b4 = ((const float4*)bs)[idx];
      float4 q4 = ((const float4*)qs)[idx];
      float4 kv;
      kv.x = (x[i].x - mean) * rstd * g4.x + b4.x;
      kv.y = (x[i].y - mean) * rstd * g4.y + b4.y;
      kv.z = (x[i].z - mean) * rstd * g4.z + b4.z;
      kv.w = (x[i].w - mean) * rstd * g4.w + b4.w;
      float p = kv.x * q4.x + kv.y * q4.y + kv.z * q4.z + kv.w * q4.w;
      p += __shfl_xor(p, 1); p += __shfl_xor(p, 2); p += __shfl_xor(p, 4);
      p += __shfl_xor(p, 8); p += __shfl_xor(p, 16);  // allreduce in 32-half
      float mn = fmaxf(m[i], p);
      float sc = __expf(m[i] - mn);
      float w = __expf(p - mn);
      s[i] = s[i] * sc + w;
      ctx[i].x = ctx[i].x * sc + w * kv.x;
      ctx[i].y = ctx[i].y * sc + w * kv.y;
      ctx[i].z = ctx[i].z * sc + w * kv.z;
      ctx[i].w = ctx[i].w * sc + w * kv.w;
      m[i] = mn;
    }
  }

  #pragma unroll
  for (int i = 0; i < 8; ++i) {
    int head = 2 * i + hi;
    size_t base = (size_t)(b * H_ + head) * NCH + ch;
    *(float4*)(pctx + base * HD_ + 4 * ll) = ctx[i];
    if (ll == 0) { pm[base] = m[i]; ps[base] = s[i]; }
  }
}

// ---------------- merge partials + apply Wv: opre[b, h*HD+e] ----------------
__global__ __launch_bounds__(128) void k_reduce(const float* __restrict__ pm,
                                                const float* __restrict__ ps,
                                                const float* __restrict__ pctx,
                                                const float* __restrict__ Wv,
                                                float* __restrict__ opre) {
  int hh = blockIdx.x, b = blockIdx.y;
  int t = threadIdx.x;
  size_t base = (size_t)(b * H_ + hh) * NCH;
  float m = -INFINITY;
  for (int c = 0; c < NCH; ++c) m = fmaxf(m, pm[base + c]);
  float stot = 0.f, acc = 0.f;
  for (int c = 0; c < NCH; ++c) {
    float wc = __expf(pm[base + c] - m);
    stot += ps[base + c] * wc;
    acc += pctx[(base + c) * HD_ + t] * wc;
  }
  float ctxn = (stot > 0.f) ? acc / stot : 0.f;
  __shared__ float cs[HD_];
  cs[t] = ctxn;
  __syncthreads();
  const float* wr = Wv + (size_t)t * HD_;
  float o = 0.f;
  for (int d = 0; d < HD_; ++d) o += wr[d] * cs[d];
  opre[(size_t)b * D_ + hh * HD_ + t] = o;
}

// ---------------- GEMM M=32: part[(b*8+kc)*D + e] = X[b][kchunk] . W[e][kchunk] -------
__global__ __launch_bounds__(256) void k_mv(const float* __restrict__ X,
                                            const float* __restrict__ W,
                                            float* __restrict__ part) {
  int et = blockIdx.x, kc = blockIdx.y;
  int t = threadIdx.x;
  __shared__ float xs[32][260];
  for (int r = 0; r < 8; ++r) {
    int i = t + 256 * r;
    int b = i >> 6, j = i & 63;
    float4 v = *(const float4*)(X + (size_t)b * D_ + kc * KCHUNK + 4 * j);
    *(float4*)(&xs[b][4 * j]) = v;
  }
  __syncthreads();
  int b = t & 31, eg = t >> 5;
  const float* wbase = W + (size_t)(et * 64 + eg * 8) * D_ + kc * KCHUNK;
  float acc[8] = {0.f, 0.f, 0.f, 0.f, 0.f, 0.f, 0.f, 0.f};
  for (int j = 0; j < 64; ++j) {
    float4 x4 = *(const float4*)(&xs[b][4 * j]);
    #pragma unroll
    for (int i = 0; i < 8; ++i) {
      float4 w4 = *(const float4*)(wbase + (size_t)i * D_ + 4 * j);
      acc[i] += w4.x * x4.x + w4.y * x4.y + w4.z * x4.z + w4.w * x4.w;
    }
  }
  float* pb = part + ((size_t)b * KSPLIT + kc) * D_ + et * 64 + eg * 8;
  float4 o0 = {acc[0], acc[1], acc[2], acc[3]};
  float4 o1 = {acc[4], acc[5], acc[6], acc[7]};
  *(float4*)pb = o0;
  *(float4*)(pb + 4) = o1;
}

// ---------------- reduce k-partials; + bias + residual; LN -> xn ----------------
__global__ __launch_bounds__(256) void k_mvred_ln(const float* __restrict__ part,
                                                  const float* __restrict__ bias,
                                                  const float* __restrict__ res,
                                                  const float* __restrict__ g,
                                                  const float* __restrict__ bvec,
                                                  float* __restrict__ xr,
                                                  float* __restrict__ xn) {
  int b = blockIdx.x, t = threadIdx.x;
  int lane = t & 63, wv = t >> 6;
  __shared__ float rs[4], rq[4];
  float4 v[2];
  float ls = 0.f, lq = 0.f;
  #pragma unroll
  for (int r = 0; r < 2; ++r) {
    int e4 = t + 256 * r;
    float4 a = {0.f, 0.f, 0.f, 0.f};
    for (int kc = 0; kc < KSPLIT; ++kc) {
      float4 p = ((const float4*)(part + ((size_t)b * KSPLIT + kc) * D_))[e4];
      a.x += p.x; a.y += p.y; a.z += p.z; a.w += p.w;
    }
    float4 b4 = ((const float4*)bias)[e4];
    float4 h4 = ((const float4*)(res + (size_t)b * D_))[e4];
    a.x += b4.x + h4.x; a.y += b4.y + h4.y; a.z += b4.z + h4.z; a.w += b4.w + h4.w;
    v[r] = a;
    ls += a.x + a.y + a.z + a.w;
    lq += a.x * a.x + a.y * a.y + a.z * a.z + a.w * a.w;
  }
  ls = wsum64(ls); lq = wsum64(lq);
  if (lane == 0) { rs[wv] = ls; rq[wv] = lq; }
  __syncthreads();
  float sum = rs[0] + rs[1] + rs[2] + rs[3];
  float sq  = rq[0] + rq[1] + rq[2] + rq[3];
  float mean = sum * (1.f / D_);
  float rstd = rsqrtf(sq * (1.f / D_) - mean * mean + EPS);
  #pragma unroll
  for (int r = 0; r < 2; ++r) {
    int e4 = t + 256 * r;
    float4 a = v[r];
    ((float4*)(xr + (size_t)b * D_))[e4] = a;
    float4 g4 = ((const float4*)g)[e4];
    float4 b4 = ((const float4*)bvec)[e4];
    float4 n;
    n.x = (a.x - mean) * rstd * g4.x + b4.x;
    n.y = (a.y - mean) * rstd * g4.y + b4.y;
    n.z = (a.z - mean) * rstd * g4.z + b4.z;
    n.w = (a.w - mean) * rstd * g4.w + b4.w;
    ((float4*)(xn + (size_t)b * D_))[e4] = n;
  }
}

// ---------------- reduce k-partials; relu(sum + bias) + optional residual ----------------
__global__ __launch_bounds__(256) void k_mvred_relu(const float* __restrict__ part,
                                                    const float* __restrict__ bias,
                                                    const float* __restrict__ res,
                                                    float* __restrict__ out) {
  int b = blockIdx.x, t = threadIdx.x;
  #pragma unroll
  for (int r = 0; r < 2; ++r) {
    int e4 = t + 256 * r;
    float4 a = {0.f, 0.f, 0.f, 0.f};
    for (int kc = 0; kc < KSPLIT; ++kc) {
      float4 p = ((const float4*)(part + ((size_t)b * KSPLIT + kc) * D_))[e4];
      a.x += p.x; a.y += p.y; a.z += p.z; a.w += p.w;
    }
    float4 b4 = ((const float4*)bias)[e4];
    a.x = fmaxf(a.x + b4.x, 0.f); a.y = fmaxf(a.y + b4.y, 0.f);
    a.z = fmaxf(a.z + b4.z, 0.f); a.w = fmaxf(a.w + b4.w, 0.f);
    if (res) {
      float4 h4 = ((const float4*)(res + (size_t)b * D_))[e4];
      a.x += h4.x; a.y += h4.y; a.z += h4.z; a.w += h4.w;
    }
    ((float4*)(out + (size_t)b * D_))[e4] = a;
  }
}

// ---------------- heads ----------------
__global__ __launch_bounds__(256) void k_heads(const float* __restrict__ hid,
                                               const float* __restrict__ aw,
                                               const float* __restrict__ ab,
                                               const float* __restrict__ cw,
                                               const float* __restrict__ cb,
                                               float* __restrict__ out) {
  int b = blockIdx.x, j = blockIdx.y;
  int t = threadIdx.x, lane = t & 63, wv = t >> 6;
  const float* wr = (j < A_) ? (aw + (size_t)j * D_) : cw;
  float acc = 0.f;
  for (int i = t; i < D_ / 4; i += 256) {
    float4 w = ((const float4*)wr)[i];
    float4 xv = ((const float4*)(hid + (size_t)b * D_))[i];
    acc += w.x * xv.x + w.y * xv.y + w.z * xv.z + w.w * xv.w;
  }
  acc = wsum64(acc);
  __shared__ float r[4];
  if (lane == 0) r[wv] = acc;
  __syncthreads();
  if (t == 0) {
    float s = r[0] + r[1] + r[2] + r[3] + ((j < A_) ? ab[j] : cb[0]);
    out[b * (A_ + 1) + j] = s;
  }
}

} // namespace

extern "C" void kernel_launch(void* const* d_in, const int* in_sizes, int n_in,
                              void* d_out, int out_size, void* d_ws, size_t ws_size,
                              hipStream_t stream) {
  (void)in_sizes; (void)n_in; (void)out_size; (void)ws_size;
  const float* x      = (const float*)d_in[0];
  const float* mem    = (const float*)d_in[1];
  const int*   mask   = (const int*)d_in[2];
  const int*   midx   = (const int*)d_in[3];
  const float* enc_w  = (const float*)d_in[4];
  const float* enc_b  = (const float*)d_in[5];
  const float* lnq_g  = (const float*)d_in[6];
  const float* lnq_b  = (const float*)d_in[7];
  const float* lnkv_g = (const float*)d_in[8];
  const float* lnkv_b = (const float*)d_in[9];
  const float* lnat_g = (const float*)d_in[10];
  const float* lnat_b = (const float*)d_in[11];
  const float* wq     = (const float*)d_in[12];
  const float* wk     = (const float*)d_in[13];
  const float* wv     = (const float*)d_in[14];
  const float* wo     = (const float*)d_in[15];
  const float* bo     = (const float*)d_in[16];
  const float* fc_w   = (const float*)d_in[17];
  const float* fc_b   = (const float*)d_in[18];
  const float* post_w = (const float*)d_in[19];
  const float* post_b = (const float*)d_in[20];
  const float* act_w  = (const float*)d_in[21];
  const float* act_b  = (const float*)d_in[22];
  const float* cri_w  = (const float*)d_in[23];
  const float* cri_b  = (const float*)d_in[24];
  float* out = (float*)d_out;

  float* ws = (float*)d_ws;
  size_t off = 0;
  float* pe   = ws + off; off += (size_t)MAXS_ * D_;
  float* h    = ws + off; off += (size_t)B_ * D_;
  float* qW   = ws + off; off += (size_t)B_ * D_;
  float* opre = ws + off; off += (size_t)B_ * D_;
  float* xr   = ws + off; off += (size_t)B_ * D_;
  float* xn   = ws + off; off += (size_t)B_ * D_;
  float* hid  = ws + off; off += (size_t)B_ * D_;
  float* pm   = ws + off; off += (size_t)B_ * H_ * NCH;
  float* ps   = ws + off; off += (size_t)B_ * H_ * NCH;
  float* pctx = ws + off; off += (size_t)B_ * H_ * NCH * HD_;
  float* part = ws + off; off += (size_t)B_ * KSPLIT * D_;

  hipLaunchKernelGGL(k_pe, dim3(MAXS_), dim3(256), 0, stream, pe);
  hipLaunchKernelGGL(k_enc, dim3(B_, D_ / 128), dim3(128), 0, stream, x, enc_w, enc_b, h);

  for (int l = 0; l < L_; ++l) {
    const float* Wq = wq + (size_t)l * HD_ * HD_;
    const float* Wk = wk + (size_t)l * HD_ * HD_;
    const float* Wv = wv + (size_t)l * HD_ * HD_;
    const float* Wo = wo + (size_t)l * D_ * D_;
    const float* Fw = fc_w + (size_t)l * D_ * D_;
    hipLaunchKernelGGL(k_qw, dim3(B_), dim3(256), 0, stream,
                       h, lnq_g + (size_t)l * D_, lnq_b + (size_t)l * D_, Wq, Wk, qW);
    hipLaunchKernelGGL(k_attn, dim3(B_, NCH / 4), dim3(256), 0, stream,
                       mem, pe, mask, midx,
                       lnkv_g + (size_t)l * D_, lnkv_b + (size_t)l * D_,
                       qW, pm, ps, pctx, l);
    hipLaunchKernelGGL(k_reduce, dim3(H_, B_), dim3(128), 0, stream,
                       pm, ps, pctx, Wv, opre);
    // xr = opre @ Wo^T + bo + h ; xn = LN(xr)
    hipLaunchKernelGGL(k_mv, dim3(D_ / 64, KSPLIT), dim3(256), 0, stream, opre, Wo, part);
    hipLaunchKernelGGL(k_mvred_ln, dim3(B_), dim3(256), 0, stream,
                       part, bo + (size_t)l * D_, h,
                       lnat_g + (size_t)l * D_, lnat_b + (size_t)l * D_, xr, xn);
    // h = relu(xn @ Fw^T + Fb) + xr
    hipLaunchKernelGGL(k_mv, dim3(D_ / 64, KSPLIT), dim3(256), 0, stream, xn, Fw, part);
    hipLaunchKernelGGL(k_mvred_relu, dim3(B_), dim3(256), 0, stream,
                       part, fc_b + (size_t)l * D_, xr, h);
  }

  // hid = relu(h @ post_w^T + post_b)
  hipLaunchKernelGGL(k_mv, dim3(D_ / 64, KSPLIT), dim3(256), 0, stream, h, post_w, part);
  hipLaunchKernelGGL(k_mvred_relu, dim3(B_), dim3(256), 0, stream,
                     part, post_b, (const float*)nullptr, hid);
  hipLaunchKernelGGL(k_heads, dim3(B_, A_ + 1), dim3(256), 0, stream,
                     hid, act_w, act_b, cri_w, cri_b, out);
}